// Round 3
// baseline (2404.356 us; speedup 1.0000x reference)
//
#include <hip/hip_runtime.h>

#define N_PTS 131072
#define DIM   64
#define CELLS 256
#define EPSF  1e-8f
#define PTS1  128   // points per block, kernel 1
#define XSTR  68    // padded x-tile row stride (dwords), %4==0 for b128
#define NB    8     // points per reduction round
#define PTS2  64    // points per block, kernel 2

// ---------------------------------------------------------------------------
// Kernel 1: distances + doubly-normalized gated weights.
// thread t <-> cell c = t. P_c, G_c live in VGPRs for the whole point tile;
// x tile in LDS read as wave-uniform broadcasts (no bank pressure).
// w store: lane <-> consecutive cell -> fully coalesced.
// ---------------------------------------------------------------------------
__global__ __launch_bounds__(256, 2)
void dist_kernel(const float* __restrict__ x,
                 const float* __restrict__ P,
                 const float* __restrict__ G,
                 const float* __restrict__ gate_logits,
                 const float* __restrict__ temp_raw,
                 float* __restrict__ w_out) {
    __shared__ float xs[PTS1 * XSTR];
    __shared__ float xn[PTS1];
    __shared__ float red[2][4][2 * NB];

    const int t    = threadIdx.x;
    const int wv   = t >> 6;
    const int lane = t & 63;
    const int c    = t;              // cell id

    // ---- per-cell constants: P/G rows into VGPRs (one-time) ----
    float pc[DIM], gc[DIM];
#pragma unroll
    for (int k = 0; k < DIM; k += 4) {
        float4 v = *reinterpret_cast<const float4*>(P + c * DIM + k);
        pc[k] = v.x; pc[k + 1] = v.y; pc[k + 2] = v.z; pc[k + 3] = v.w;
        float4 u = *reinterpret_cast<const float4*>(G + c * DIM + k);
        gc[k] = u.x; gc[k + 1] = u.y; gc[k + 2] = u.z; gc[k + 3] = u.w;
    }
    float pn = 0.f, gn = 0.f;
#pragma unroll
    for (int k = 0; k < DIM; ++k) {
        pn = fmaf(pc[k], pc[k], pn);
        gn = fmaf(gc[k], gc[k], gn);
    }
    const float gate = 1.f / (1.f + expf(-gate_logits[c]));
    const float trw  = temp_raw[0];
    const float temp = (1.f / (1.f + expf(-trw))) * (1.f - 0.001f) + 0.001f;
    const float cscale = -1.4426950408889634f / temp;  // -log2(e)/temp

    // ---- stage x tile (coalesced global float4 -> padded LDS) ----
    const float4* xsrc = reinterpret_cast<const float4*>(
        x + (size_t)blockIdx.x * PTS1 * DIM);
#pragma unroll
    for (int j = 0; j < (PTS1 * DIM / 4) / 256; ++j) {   // 8
        int f = j * 256 + t;                             // float4 index
        float4 v = xsrc[f];
        int row = f >> 4;                                // 16 float4 per row
        int col = (f & 15) << 2;
        *reinterpret_cast<float4*>(&xs[row * XSTR + col]) = v;
    }
    __syncthreads();
    // ---- xn per point: 2 threads per row ----
    {
        int row = t >> 1, half = t & 1;
        const float* rp = &xs[row * XSTR + half * 32];
        float a = 0.f;
#pragma unroll
        for (int k = 0; k < 32; k += 4) {
            float4 v = *reinterpret_cast<const float4*>(rp + k);
            a = fmaf(v.x, v.x, fmaf(v.y, v.y, fmaf(v.z, v.z, fmaf(v.w, v.w, a))));
        }
        a += __shfl_xor(a, 1);
        if (half == 0) xn[row] = a;
    }
    __syncthreads();

    float* wbase = w_out + (size_t)blockIdx.x * PTS1 * CELLS;

    int buf = 0;
#pragma unroll 1
    for (int p0 = 0; p0 < PTS1; p0 += NB) {
        float ev[NB], tv[NB];
#pragma unroll
        for (int q = 0; q < NB; ++q) {
            const float* xrow = &xs[(p0 + q) * XSTR];
            float a0 = 0.f, a1 = 0.f, a2 = 0.f, a3 = 0.f;
            float b0 = 0.f, b1 = 0.f, b2 = 0.f, b3 = 0.f;
#pragma unroll
            for (int k = 0; k < DIM; k += 4) {
                float4 xv = *reinterpret_cast<const float4*>(xrow + k); // uniform
                a0 = fmaf(xv.x, pc[k + 0], a0);
                a1 = fmaf(xv.y, pc[k + 1], a1);
                a2 = fmaf(xv.z, pc[k + 2], a2);
                a3 = fmaf(xv.w, pc[k + 3], a3);
                b0 = fmaf(xv.x, gc[k + 0], b0);
                b1 = fmaf(xv.y, gc[k + 1], b1);
                b2 = fmaf(xv.z, gc[k + 2], b2);
                b3 = fmaf(xv.w, gc[k + 3], b3);
            }
            float dotp = (a0 + a1) + (a2 + a3);
            float dotg = (b0 + b1) + (b2 + b3);
            float xnq  = xn[p0 + q];
            float dp2  = fmaf(-2.f, dotp, xnq + pn);
            float dg2  = fmaf(-2.f, dotg, xnq + gn);
            float d    = sqrtf(fmaxf(dp2, 0.f)) + sqrtf(fmaxf(dg2, 0.f));
            float e    = exp2f(d * cscale);    // exp(-d/temp)
            ev[q] = e;
            tv[q] = e * gate;
        }
        // ---- wave butterfly sums (all lanes end with wave totals) ----
#pragma unroll
        for (int q = 0; q < NB; ++q) {
            float se = ev[q], st = tv[q];
#pragma unroll
            for (int m = 1; m < 64; m <<= 1) {
                se += __shfl_xor(se, m);
                st += __shfl_xor(st, m);
            }
            if (lane == 0) {
                red[buf][wv][q]      = se;
                red[buf][wv][NB + q] = st;
            }
        }
        __syncthreads();
#pragma unroll
        for (int q = 0; q < NB; ++q) {
            float s1 = red[buf][0][q] + red[buf][1][q]
                     + red[buf][2][q] + red[buf][3][q];
            float sg = red[buf][0][NB + q] + red[buf][1][NB + q]
                     + red[buf][2][NB + q] + red[buf][3][NB + q];
            // ref: w1=e/(s1+eps); t1=w1*gate; s2=sum t1; w2=t1/(s2+eps)
            //   => w2 = (e*gate) / ((s1+eps)*(s2+eps))
            float A     = s1 + EPSF;
            float s2    = sg / A;
            float alpha = 1.f / (A * (s2 + EPSF));
            wbase[(size_t)(p0 + q) * CELLS + c] = tv[q] * alpha;  // coalesced
        }
        buf ^= 1;  // double-buffered red -> one barrier per round
    }
}

// ---------------------------------------------------------------------------
// Kernel 2: blended = w2 @ P.  64-point w tile in exactly-64KB LDS with a
// float4-chunk XOR swizzle (kills the stride-1KB bank collision); wave wv
// owns dim chunk [16*wv,+16) (P read wave-uniform -> s_load); lane <-> point.
// ---------------------------------------------------------------------------
__global__ __launch_bounds__(256, 4)
void blend_kernel(const float* __restrict__ w_in,
                  const float* __restrict__ P,
                  float* __restrict__ bl) {
    __shared__ float wt[PTS2 * CELLS];   // 65536 B exactly
    const int t    = threadIdx.x;
    const int wv   = t >> 6;
    const int lane = t & 63;
    const size_t pbase = (size_t)blockIdx.x * PTS2;

    // ---- stage w tile, swizzled: dword(p,c) = p*256 + ((c>>2 ^ (p&7))<<2) + (c&3)
#pragma unroll
    for (int j = 0; j < (PTS2 * CELLS / 4) / 256; ++j) {   // 16
        int f  = j * 256 + t;          // float4 index
        int p  = f >> 6;               // 64 float4 per row (uniform per wave)
        int ch = f & 63;               // chunk = c>>2 (== lane) -> coalesced
        float4 v = reinterpret_cast<const float4*>(w_in + (pbase + p) * CELLS)[ch];
        *reinterpret_cast<float4*>(&wt[p * CELLS + ((ch ^ (p & 7)) << 2)]) = v;
    }
    __syncthreads();

    const int p  = lane;        // point within tile
    const int d0 = wv * 16;     // dim chunk
    float b[16];
#pragma unroll
    for (int j = 0; j < 16; ++j) b[j] = 0.f;

#pragma unroll 2
    for (int c0 = 0; c0 < CELLS; c0 += 4) {
        float4 wq = *reinterpret_cast<const float4*>(
            &wt[p * CELLS + ((((c0 >> 2) ^ (p & 7))) << 2)]);
        const float w4[4] = {wq.x, wq.y, wq.z, wq.w};
#pragma unroll
        for (int cc = 0; cc < 4; ++cc) {
            const float* prow = P + (c0 + cc) * DIM + d0;  // wave-uniform -> s_load
            float wgt = w4[cc];
#pragma unroll
            for (int j = 0; j < 16; ++j)
                b[j] = fmaf(wgt, prow[j], b[j]);
        }
    }

    float* orow = bl + (pbase + p) * DIM + d0;
#pragma unroll
    for (int j = 0; j < 16; j += 4)
        *reinterpret_cast<float4*>(orow + j) =
            make_float4(b[j], b[j + 1], b[j + 2], b[j + 3]);
}

extern "C" void kernel_launch(void* const* d_in, const int* in_sizes, int n_in,
                              void* d_out, int out_size, void* d_ws, size_t ws_size,
                              hipStream_t stream) {
    const float* x           = (const float*)d_in[0];
    const float* prototypes  = (const float*)d_in[1];
    const float* grid_pos    = (const float*)d_in[2];
    const float* gate_logits = (const float*)d_in[3];
    const float* temp_raw    = (const float*)d_in[4];
    float*       out         = (float*)d_out;
    float*       blended     = out;                              // [N, 64]
    float*       w           = out + (size_t)N_PTS * DIM;        // [N, 256]

    dist_kernel<<<N_PTS / PTS1, 256, 0, stream>>>(
        x, prototypes, grid_pos, gate_logits, temp_raw, w);
    blend_kernel<<<N_PTS / PTS2, 256, 0, stream>>>(w, prototypes, blended);
}

// Round 4
// 738.711 us; speedup vs baseline: 3.2548x; 3.2548x over previous
//
#include <hip/hip_runtime.h>

#define N_PTS 131072
#define DIM   64
#define CELLS 256
#define EPSF  1e-8f
#define PTS2  64     // points per block, blend kernel

// ws layout (floats): [0..255]=||P_c||^2  [256..511]=||G_c||^2
//                     [512..767]=gate     [768]=cscale
//                     [1024..1024+N)=alpha per point
#define WS_ALPHA 1024

// ---------------------------------------------------------------------------
// prep: per-cell norms, gate=sigmoid(gate_logits), cscale=-log2(e)/temp
// ---------------------------------------------------------------------------
__global__ void prep_kernel(const float* __restrict__ prototypes,
                            const float* __restrict__ grid_pos,
                            const float* __restrict__ gate_logits,
                            const float* __restrict__ temp_raw,
                            float* __restrict__ ws) {
    const int c = threadIdx.x;  // 256 threads, 1 block
    const float* p = prototypes + c * DIM;
    const float* g = grid_pos   + c * DIM;
    float pn = 0.f, gn = 0.f;
#pragma unroll
    for (int k = 0; k < DIM; ++k) {
        pn = fmaf(p[k], p[k], pn);
        gn = fmaf(g[k], g[k], gn);
    }
    ws[c]             = pn;
    ws[CELLS + c]     = gn;
    ws[2 * CELLS + c] = 1.f / (1.f + expf(-gate_logits[c]));
    if (c == 0) {
        float sg   = 1.f / (1.f + expf(-temp_raw[0]));
        float temp = sg * (1.f - 0.001f) + 0.001f;
        ws[3 * CELLS] = -1.4426950408889634f / temp;  // -log2(e)/temp
    }
}

// ---- x row as 16 NAMED float4s (SSA; arrays get demoted to scratch) ----
#define D4(xa, b, row, A_) \
    A_##0 = fmaf(xa.x, row[b + 0], A_##0); \
    A_##1 = fmaf(xa.y, row[b + 1], A_##1); \
    A_##2 = fmaf(xa.z, row[b + 2], A_##2); \
    A_##3 = fmaf(xa.w, row[b + 3], A_##3);

#define DOT64(row, A_) \
    D4(x0, 0, row, A_)  D4(x1, 4, row, A_)  D4(x2, 8, row, A_)  D4(x3, 12, row, A_) \
    D4(x4, 16, row, A_) D4(x5, 20, row, A_) D4(x6, 24, row, A_) D4(x7, 28, row, A_) \
    D4(x8, 32, row, A_) D4(x9, 36, row, A_) D4(x10, 40, row, A_) D4(x11, 44, row, A_) \
    D4(x12, 48, row, A_) D4(x13, 52, row, A_) D4(x14, 56, row, A_) D4(x15, 60, row, A_)

#define XN4(xa) \
    xn0 = fmaf(xa.x, xa.x, xn0); xn1 = fmaf(xa.y, xa.y, xn1); \
    xn2 = fmaf(xa.z, xa.z, xn2); xn3 = fmaf(xa.w, xa.w, xn3);

// ---------------------------------------------------------------------------
// dist: thread <-> point. x in 64 VGPRs; P/G rows wave-uniform s_load.
// Writes UNSCALED t = e*gate to w, and alpha per point to ws.
// ---------------------------------------------------------------------------
__global__ __launch_bounds__(256, 2)
void dist_kernel(const float* __restrict__ x,
                 const float* __restrict__ P,
                 const float* __restrict__ G,
                 const float* __restrict__ ws,
                 float* __restrict__ w_out,
                 float* __restrict__ alpha_out) {
    const int i = blockIdx.x * 256 + threadIdx.x;

    const float4* xp = reinterpret_cast<const float4*>(x) + (size_t)i * 16;
    float4 x0 = xp[0],  x1 = xp[1],  x2 = xp[2],  x3 = xp[3];
    float4 x4 = xp[4],  x5 = xp[5],  x6 = xp[6],  x7 = xp[7];
    float4 x8 = xp[8],  x9 = xp[9],  x10 = xp[10], x11 = xp[11];
    float4 x12 = xp[12], x13 = xp[13], x14 = xp[14], x15 = xp[15];

    float xn0 = 0.f, xn1 = 0.f, xn2 = 0.f, xn3 = 0.f;
    XN4(x0) XN4(x1) XN4(x2) XN4(x3) XN4(x4) XN4(x5) XN4(x6) XN4(x7)
    XN4(x8) XN4(x9) XN4(x10) XN4(x11) XN4(x12) XN4(x13) XN4(x14) XN4(x15)
    const float xn = (xn0 + xn1) + (xn2 + xn3);

    const float cscale = ws[3 * CELLS];
    float s1 = 0.f, sg = 0.f;
    float* wrow = w_out + (size_t)i * CELLS;

#define CELL(cc, tvar) { \
    const int c = c0 + cc; \
    const float* __restrict__ pr = P + c * DIM; \
    float pa0 = 0.f, pa1 = 0.f, pa2 = 0.f, pa3 = 0.f; \
    DOT64(pr, pa) \
    const float* __restrict__ gr = G + c * DIM; \
    float ga0 = 0.f, ga1 = 0.f, ga2 = 0.f, ga3 = 0.f; \
    DOT64(gr, ga) \
    float dotp = (pa0 + pa1) + (pa2 + pa3); \
    float dotg = (ga0 + ga1) + (ga2 + ga3); \
    float dp2 = fmaf(-2.f, dotp, xn + ws[c]); \
    float dg2 = fmaf(-2.f, dotg, xn + ws[CELLS + c]); \
    float dtot = sqrtf(fmaxf(dp2, 0.f)) + sqrtf(fmaxf(dg2, 0.f)); \
    float e = exp2f(dtot * cscale); \
    s1 += e; \
    tvar = e * ws[2 * CELLS + c]; \
    sg += tvar; }

#pragma unroll 1
    for (int c0 = 0; c0 < CELLS; c0 += 4) {
        float t0, t1, t2, t3;
        CELL(0, t0) CELL(1, t1) CELL(2, t2) CELL(3, t3)
        *reinterpret_cast<float4*>(wrow + c0) = make_float4(t0, t1, t2, t3);
    }
#undef CELL

    // ref: w1=e/(s1+eps); t1=w1*gate; s2=sum t1; w2=t1/(s2+eps)
    //   => w2 = (e*gate) * alpha,  alpha = 1/((s1+eps)*(s2+eps))
    const float A  = s1 + EPSF;
    const float s2 = sg / A;
    alpha_out[i] = 1.f / (A * (s2 + EPSF));
}

// ---------------------------------------------------------------------------
// blend: w2 = t*alpha (write-back) and blended = w2 @ P.
// 64-pt w tile in 64KB LDS, chunk-XOR swizzle (row-stride is bank-neutral;
// XOR spreads the per-row column read across all 8 bank-quads -> 8-phase-
// optimal b128). wave<->dim-chunk, lane<->point; P rows wave-uniform s_load.
// ---------------------------------------------------------------------------
__global__ __launch_bounds__(256, 2)
void blend_kernel(float* w,                       // in: t, out: t*alpha
                  const float* __restrict__ P,
                  const float* __restrict__ alphap,
                  float* __restrict__ bl) {
    __shared__ float wt[PTS2 * CELLS];   // 65536 B
    __shared__ float als[PTS2];
    const int t    = threadIdx.x;
    const int wv   = t >> 6;
    const int lane = t & 63;
    const size_t pbase = (size_t)blockIdx.x * PTS2;

    // stage w tile (coalesced global read; swizzled LDS write)
#pragma unroll
    for (int j = 0; j < 16; ++j) {
        int f  = j * 256 + t;
        int p  = f >> 6;               // wave-uniform (= j*4 + wv)
        int ch = f & 63;               // = lane -> coalesced
        float4 v = reinterpret_cast<const float4*>(w + (pbase + p) * CELLS)[ch];
        *reinterpret_cast<float4*>(&wt[p * CELLS + ((ch ^ (p & 7)) << 2)]) = v;
    }
    if (t < PTS2) als[t] = alphap[pbase + t];
    __syncthreads();

    const int p  = lane;        // point within tile
    const int d0 = wv * 16;     // dim chunk
    float bb0 = 0.f, bb1 = 0.f, bb2 = 0.f, bb3 = 0.f;
    float bb4 = 0.f, bb5 = 0.f, bb6 = 0.f, bb7 = 0.f;
    float bb8 = 0.f, bb9 = 0.f, bb10 = 0.f, bb11 = 0.f;
    float bb12 = 0.f, bb13 = 0.f, bb14 = 0.f, bb15 = 0.f;

#define BSTEP(cc) { \
    const float* __restrict__ prow = P + (c0 + cc) * DIM + d0; \
    const float wgt = w4[cc]; \
    bb0  = fmaf(wgt, prow[0],  bb0);  bb1  = fmaf(wgt, prow[1],  bb1); \
    bb2  = fmaf(wgt, prow[2],  bb2);  bb3  = fmaf(wgt, prow[3],  bb3); \
    bb4  = fmaf(wgt, prow[4],  bb4);  bb5  = fmaf(wgt, prow[5],  bb5); \
    bb6  = fmaf(wgt, prow[6],  bb6);  bb7  = fmaf(wgt, prow[7],  bb7); \
    bb8  = fmaf(wgt, prow[8],  bb8);  bb9  = fmaf(wgt, prow[9],  bb9); \
    bb10 = fmaf(wgt, prow[10], bb10); bb11 = fmaf(wgt, prow[11], bb11); \
    bb12 = fmaf(wgt, prow[12], bb12); bb13 = fmaf(wgt, prow[13], bb13); \
    bb14 = fmaf(wgt, prow[14], bb14); bb15 = fmaf(wgt, prow[15], bb15); }

#pragma unroll 2
    for (int c0 = 0; c0 < CELLS; c0 += 4) {
        float4 wq = *reinterpret_cast<const float4*>(
            &wt[p * CELLS + ((((c0 >> 2) ^ (p & 7))) << 2)]);
        const float w4[4] = {wq.x, wq.y, wq.z, wq.w};
        BSTEP(0) BSTEP(1) BSTEP(2) BSTEP(3)
    }
#undef BSTEP

    // blended row (alpha folded once at the end)
    const float al = als[p];
    float* orow = bl + (pbase + p) * DIM + d0;
    *reinterpret_cast<float4*>(orow + 0)  = make_float4(bb0 * al,  bb1 * al,  bb2 * al,  bb3 * al);
    *reinterpret_cast<float4*>(orow + 4)  = make_float4(bb4 * al,  bb5 * al,  bb6 * al,  bb7 * al);
    *reinterpret_cast<float4*>(orow + 8)  = make_float4(bb8 * al,  bb9 * al,  bb10 * al, bb11 * al);
    *reinterpret_cast<float4*>(orow + 12) = make_float4(bb12 * al, bb13 * al, bb14 * al, bb15 * al);

    // write back scaled w (coalesced; reads LDS, no wt mutation -> no barrier)
#pragma unroll
    for (int j = 0; j < 16; ++j) {
        int f  = j * 256 + t;
        int pp = f >> 6;               // wave-uniform
        int ch = f & 63;
        float4 v = *reinterpret_cast<const float4*>(
            &wt[pp * CELLS + ((ch ^ (pp & 7)) << 2)]);
        const float a = als[pp];       // uniform LDS read
        v.x *= a; v.y *= a; v.z *= a; v.w *= a;
        reinterpret_cast<float4*>(w + (pbase + pp) * CELLS)[ch] = v;
    }
}

extern "C" void kernel_launch(void* const* d_in, const int* in_sizes, int n_in,
                              void* d_out, int out_size, void* d_ws, size_t ws_size,
                              hipStream_t stream) {
    const float* x           = (const float*)d_in[0];
    const float* prototypes  = (const float*)d_in[1];
    const float* grid_pos    = (const float*)d_in[2];
    const float* gate_logits = (const float*)d_in[3];
    const float* temp_raw    = (const float*)d_in[4];
    float*       out         = (float*)d_out;
    float*       blended     = out;                           // [N, 64]
    float*       w           = out + (size_t)N_PTS * DIM;     // [N, 256]
    float*       ws          = (float*)d_ws;
    float*       alpha       = ws + WS_ALPHA;                 // N floats

    prep_kernel<<<1, CELLS, 0, stream>>>(prototypes, grid_pos, gate_logits,
                                         temp_raw, ws);
    dist_kernel<<<N_PTS / 256, 256, 0, stream>>>(x, prototypes, grid_pos, ws,
                                                 w, alpha);
    blend_kernel<<<N_PTS / PTS2, 256, 0, stream>>>(w, prototypes, alpha, blended);
}